// Round 8
// baseline (62.523 us; speedup 1.0000x reference)
//
#include <hip/hip_runtime.h>

// SingleCurveDeformLayer: 2-step Euler RBF flow, fused single kernel with a
// per-batch src-writer barrier.
//   Phase A: shape1_i = land_i + TAU*sum_j exp(-|land_i - src_j|^2/s2)*mom_j
//   Phase B: out_i    = shape1_i + TAU*sum_j exp(-|shape1_i-shape1_j|^2/s2)*mom_j (tgt i)
//
// Grid: B * 256 blocks of 256 threads (4 waves). Per batch: 128 "src" blocks
// compute shape1 for the 2048 source points, store them PRE-SCALED to ws
// (plain float4 stores), fence(release,agent)+atomicAdd, exit. 128 "tgt"
// blocks compute shape1 for their 16 target points (kept in registers: after
// the xor-butterfly every lane holds the sums), spin until cnt[b]==128,
// fence(acquire,agent) -> plain cached loads are then coherent (ROCm
// grid-sync protocol: wbl2 on release, buffer_inv on acquire).
// All 1024 blocks co-resident (32KB LDS -> 4/CU used, cap 5; ~50 VGPR) so
// spinning cannot deadlock.
//
// Per-pair math: coords pre-scaled by sqrt(log2e/sigma^2) so
// w = exp2(-(dx^2+dy^2)) (negation = free v_exp input modifier); TAU folded
// into staged momenta. 6 VALU + 1 trans per pair.

typedef unsigned int u32;

constexpr int N    = 2048;            // n_src == n_tgt
constexpr int TPB  = 256;             // 4 waves
constexpr int MP   = 4;               // i-points per lane (per wave)
constexpr int PPA  = (TPB / 64) * MP; // 16 points per block
constexpr int NJ   = N / 64;          // 32 j-iterations per lane
constexpr int BPB  = 2 * N / PPA;     // 256 blocks per batch
constexpr int SRCB = N / PPA;         // 128 src blocks per batch
constexpr float TAU   = 0.5f;         // 1/(N_T-1), N_T=3
constexpr float LOG2E = 1.44269504088896340736f;

__device__ inline float exp2_neg(float x) {   // 2^(-x), free neg modifier
    return __builtin_amdgcn_exp2f(-x);
}

__global__ __launch_bounds__(TPB, 4)
void deform_fused(const float* __restrict__ momentum,
                  const float* __restrict__ source_init,
                  const float* __restrict__ target_init,
                  const float* __restrict__ sigmaV2,
                  float* __restrict__ ws_sxy,   // [B][N][2] scaled src shape1
                  u32*   __restrict__ cnt,      // B counters, 64B stride
                  float* __restrict__ out)      // [B][N][2]
{
    __shared__ float2 sxy[N];   // scaled j coords (16 KB)
    __shared__ float2 smo[N];   // TAU * j momenta (16 KB)

    const int tid  = threadIdx.x;
    const int b    = blockIdx.x / BPB;
    const int r    = blockIdx.x % BPB;
    const bool is_src = (r < SRCB);
    const int pblk = is_src ? r : r - SRCB;

    const float scale = sqrtf(LOG2E / sigmaV2[0]);

    // ---- phase-A staging: scaled src coords + TAU*mom ----
    for (int k4 = tid; k4 < N / 2; k4 += TPB) {          // 4 iters
        const float4 p = ((const float4*)source_init)[b * (N / 2) + k4];
        const float4 m = ((const float4*)momentum  )[b * (N / 2) + k4];
        sxy[2 * k4 + 0] = make_float2(p.x * scale, p.y * scale);
        sxy[2 * k4 + 1] = make_float2(p.z * scale, p.w * scale);
        smo[2 * k4 + 0] = make_float2(m.x * TAU, m.y * TAU);
        smo[2 * k4 + 1] = make_float2(m.z * TAU, m.w * TAU);
    }

    const int lane = tid & 63;
    const int g    = tid >> 6;
    const int pi0  = pblk * PPA + g * MP;   // index within src or tgt half

    const float* ibase = is_src ? source_init : target_init;
    const float4 pa  = ((const float4*)ibase)[(b * N + pi0) >> 1];
    const float4 pb4 = ((const float4*)ibase)[(b * N + pi0 + 2) >> 1];
    float xr[MP] = {pa.x, pa.z, pb4.x, pb4.z};   // raw i coords
    float yr[MP] = {pa.y, pa.w, pb4.y, pb4.w};
    float xs[MP], ys[MP];
    #pragma unroll
    for (int m = 0; m < MP; ++m) { xs[m] = xr[m] * scale; ys[m] = yr[m] * scale; }
    __syncthreads();

    // ---- phase A j-loop ----
    float ax[MP] = {0, 0, 0, 0}, ay[MP] = {0, 0, 0, 0};
    #pragma unroll 4
    for (int t = 0; t < NJ; ++t) {
        const float2 s  = sxy[t * 64 + lane];
        const float2 mo = smo[t * 64 + lane];
        #pragma unroll
        for (int m = 0; m < MP; ++m) {
            const float dx = xs[m] - s.x, dy = ys[m] - s.y;
            const float w  = exp2_neg(fmaf(dy, dy, dx * dx));
            ax[m] = fmaf(w, mo.x, ax[m]);  ay[m] = fmaf(w, mo.y, ay[m]);
        }
    }
    #pragma unroll
    for (int d = 1; d < 64; d <<= 1) {
        #pragma unroll
        for (int m = 0; m < MP; ++m) {
            ax[m] += __shfl_xor(ax[m], d);  ay[m] += __shfl_xor(ay[m], d);
        }
    }
    #pragma unroll
    for (int m = 0; m < MP; ++m) { xr[m] += ax[m]; yr[m] += ay[m]; }  // raw shape1

    u32* c = cnt + b * 16;   // 64B-strided counters

    if (is_src) {
        // store scaled src shape1 for phase B, then signal and exit
        if (lane == 0) {
            const float4 o0 = make_float4(xr[0] * scale, yr[0] * scale,
                                          xr[1] * scale, yr[1] * scale);
            const float4 o1 = make_float4(xr[2] * scale, yr[2] * scale,
                                          xr[3] * scale, yr[3] * scale);
            ((float4*)ws_sxy)[(b * N + pi0) >> 1]     = o0;
            ((float4*)ws_sxy)[(b * N + pi0 + 2) >> 1] = o1;
        }
        __syncthreads();   // all waves' stores issued & drained before signal
        if (tid == 0) {
            __builtin_amdgcn_fence(__ATOMIC_RELEASE, "agent");
            __hip_atomic_fetch_add(c, 1u, __ATOMIC_RELAXED, __HIP_MEMORY_SCOPE_AGENT);
        }
        return;
    }

    // ---- tgt blocks: wait for this batch's 128 src writers ----
    if (tid == 0) {
        while (__hip_atomic_load(c, __ATOMIC_RELAXED, __HIP_MEMORY_SCOPE_AGENT)
               < (u32)SRCB) {
            __builtin_amdgcn_s_sleep(2);
        }
    }
    __syncthreads();
    __builtin_amdgcn_fence(__ATOMIC_ACQUIRE, "agent");

    // ---- phase-B staging: overwrite sxy with scaled src shape1 ----
    for (int k4 = tid; k4 < N / 2; k4 += TPB) {          // 4 iters
        const float4 p = ((const float4*)ws_sxy)[b * (N / 2) + k4];
        sxy[2 * k4 + 0] = make_float2(p.x, p.y);
        sxy[2 * k4 + 1] = make_float2(p.z, p.w);
    }
    float xsB[MP], ysB[MP];
    #pragma unroll
    for (int m = 0; m < MP; ++m) { xsB[m] = xr[m] * scale; ysB[m] = yr[m] * scale; }
    __syncthreads();

    // ---- phase B j-loop ----
    float bx[MP] = {0, 0, 0, 0}, by[MP] = {0, 0, 0, 0};
    #pragma unroll 4
    for (int t = 0; t < NJ; ++t) {
        const float2 s  = sxy[t * 64 + lane];
        const float2 mo = smo[t * 64 + lane];
        #pragma unroll
        for (int m = 0; m < MP; ++m) {
            const float dx = xsB[m] - s.x, dy = ysB[m] - s.y;
            const float w  = exp2_neg(fmaf(dy, dy, dx * dx));
            bx[m] = fmaf(w, mo.x, bx[m]);  by[m] = fmaf(w, mo.y, by[m]);
        }
    }
    #pragma unroll
    for (int d = 1; d < 64; d <<= 1) {
        #pragma unroll
        for (int m = 0; m < MP; ++m) {
            bx[m] += __shfl_xor(bx[m], d);  by[m] += __shfl_xor(by[m], d);
        }
    }
    if (lane == 0) {
        const float4 o0 = make_float4(xr[0] + bx[0], yr[0] + by[0],
                                      xr[1] + bx[1], yr[1] + by[1]);
        const float4 o1 = make_float4(xr[2] + bx[2], yr[2] + by[2],
                                      xr[3] + bx[3], yr[3] + by[3]);
        ((float4*)out)[(b * N + pi0) >> 1]     = o0;
        ((float4*)out)[(b * N + pi0 + 2) >> 1] = o1;
    }
}

extern "C" void kernel_launch(void* const* d_in, const int* in_sizes, int n_in,
                              void* d_out, int out_size, void* d_ws, size_t ws_size,
                              hipStream_t stream)
{
    const float* momentum    = (const float*)d_in[0];
    const float* source_init = (const float*)d_in[1];
    const float* target_init = (const float*)d_in[2];
    const float* sigmaV2     = (const float*)d_in[3];
    float* out = (float*)d_out;

    const int B = in_sizes[0] / (N * 2);        // 4

    float* ws_sxy = (float*)d_ws;                                  // B*N*2 floats
    u32*   cnt    = (u32*)((char*)d_ws + (size_t)B * N * 2 * sizeof(float));

    // reset per-batch barrier counters (B * 64 bytes) every call
    (void)hipMemsetAsync(cnt, 0, (size_t)B * 16 * sizeof(u32), stream);

    deform_fused<<<dim3(B * BPB), dim3(TPB), 0, stream>>>(
        momentum, source_init, target_init, sigmaV2, ws_sxy, cnt, out);
}

// Round 9
// 42.352 us; speedup vs baseline: 1.4763x; 1.4763x over previous
//
#include <hip/hip_runtime.h>

// SingleCurveDeformLayer: 2-step Euler RBF flow, fused single kernel, v3.
//   Phase A: shape1_i = land_i + TAU*sum_j exp(-|land_i - src_j|^2/s2)*mom_j
//   Phase B: out_i    = shape1_i + TAU*sum_j exp(-|shape1_i-shape1_j|^2/s2)*mom_j (tgt i)
//
// R8 lesson (rocprof: deform_fused 54us, VALUBusy 17%): per-block agent-scope
// FENCES (buffer_wbl2 / buffer_inv = full L2 flush/inv per block x 512) cost
// ~45us. v3 uses ZERO fences: cross-XCD handoff goes through per-access
// coherent ops only --
//   src writers : 8B agent-scope relaxed atomic stores (sc0/sc1 -> LLC, the
//                 die-level coherence point shared by all XCDs), then inline
//                 s_waitcnt vmcnt(0) (orders stores before signal, no cache
//                 maintenance), then relaxed fetch_add on the batch counter.
//   tgt readers : relaxed poll on counter, __syncthreads, then 8B agent-scope
//                 relaxed atomic loads (bypass stale L1/L2, read LLC).
// All 1024 blocks co-resident (32KB LDS = 4/CU of cap 5, ~48 VGPR), so the
// spin cannot deadlock regardless of dispatch order.
//
// Per-pair math: coords pre-scaled by sqrt(log2e/sigma^2) so
// w = exp2(-(dx^2+dy^2)) (negation = free v_exp input modifier); TAU folded
// into staged momenta. Single float4 LDS array -> 1 ds_read_b128 per j-iter.

typedef unsigned int u32;
typedef unsigned long long u64;

constexpr int N    = 2048;            // n_src == n_tgt
constexpr int TPB  = 256;             // 4 waves
constexpr int MP   = 4;               // i-points per lane (per wave)
constexpr int PPA  = (TPB / 64) * MP; // 16 points per block
constexpr int NJ   = N / 64;          // 32 j-iterations per lane
constexpr int BPB  = 2 * N / PPA;     // 256 blocks per batch
constexpr int SRCB = N / PPA;         // 128 src blocks per batch
constexpr float TAU   = 0.5f;         // 1/(N_T-1), N_T=3
constexpr float LOG2E = 1.44269504088896340736f;

__device__ inline float exp2_neg(float x) {   // 2^(-x), free neg modifier
    return __builtin_amdgcn_exp2f(-x);
}

union F2U { float2 f; u64 u; };

__device__ inline void store_f2_agent(float* p, float x, float y) {
    F2U v; v.f = make_float2(x, y);
    __hip_atomic_store((u64*)p, v.u, __ATOMIC_RELAXED, __HIP_MEMORY_SCOPE_AGENT);
}
__device__ inline float2 load_f2_agent(const float* p) {
    F2U v; v.u = __hip_atomic_load((const u64*)p, __ATOMIC_RELAXED, __HIP_MEMORY_SCOPE_AGENT);
    return v.f;
}

__global__ __launch_bounds__(TPB, 4)
void deform_fused(const float* __restrict__ momentum,
                  const float* __restrict__ source_init,
                  const float* __restrict__ target_init,
                  const float* __restrict__ sigmaV2,
                  float* __restrict__ ws_sxy,   // [B][N][2] scaled src shape1
                  u32*   __restrict__ cnt,      // B counters, 64B stride
                  float* __restrict__ out)      // [B][N][2]
{
    __shared__ float4 sj[N];   // (s*x, s*y, TAU*mx, TAU*my): 32 KB

    const int tid  = threadIdx.x;
    const int b    = blockIdx.x / BPB;
    const int r    = blockIdx.x % BPB;
    const bool is_src = (r < SRCB);
    const int pblk = is_src ? r : r - SRCB;

    const float scale = sqrtf(LOG2E / sigmaV2[0]);

    // ---- phase-A staging: scaled src coords + TAU*mom (float4 = 2 pts) ----
    for (int k4 = tid; k4 < N / 2; k4 += TPB) {          // 4 iters
        const float4 p = ((const float4*)source_init)[b * (N / 2) + k4];
        const float4 m = ((const float4*)momentum  )[b * (N / 2) + k4];
        sj[2 * k4 + 0] = make_float4(p.x * scale, p.y * scale, m.x * TAU, m.y * TAU);
        sj[2 * k4 + 1] = make_float4(p.z * scale, p.w * scale, m.z * TAU, m.w * TAU);
    }

    const int lane = tid & 63;
    const int g    = tid >> 6;
    const int pi0  = pblk * PPA + g * MP;   // index within src or tgt half

    const float* ibase = is_src ? source_init : target_init;
    const float4 pa  = ((const float4*)ibase)[(b * N + pi0) >> 1];
    const float4 pb4 = ((const float4*)ibase)[(b * N + pi0 + 2) >> 1];
    float xr[MP] = {pa.x, pa.z, pb4.x, pb4.z};   // raw i coords
    float yr[MP] = {pa.y, pa.w, pb4.y, pb4.w};
    float xs[MP], ys[MP];
    #pragma unroll
    for (int m = 0; m < MP; ++m) { xs[m] = xr[m] * scale; ys[m] = yr[m] * scale; }
    __syncthreads();

    // ---- phase A j-loop ----
    float ax[MP] = {0, 0, 0, 0}, ay[MP] = {0, 0, 0, 0};
    #pragma unroll 4
    for (int t = 0; t < NJ; ++t) {
        const float4 s = sj[t * 64 + lane];
        #pragma unroll
        for (int m = 0; m < MP; ++m) {
            const float dx = xs[m] - s.x, dy = ys[m] - s.y;
            const float w  = exp2_neg(fmaf(dy, dy, dx * dx));
            ax[m] = fmaf(w, s.z, ax[m]);  ay[m] = fmaf(w, s.w, ay[m]);
        }
    }
    #pragma unroll
    for (int d = 1; d < 64; d <<= 1) {
        #pragma unroll
        for (int m = 0; m < MP; ++m) {
            ax[m] += __shfl_xor(ax[m], d);  ay[m] += __shfl_xor(ay[m], d);
        }
    }
    #pragma unroll
    for (int m = 0; m < MP; ++m) { xr[m] += ax[m]; yr[m] += ay[m]; }  // raw shape1

    u32* c = cnt + b * 16;   // 64B-strided counters

    if (is_src) {
        // publish scaled src shape1 via LLC-coherent 8B stores, then signal
        if (lane == 0) {
            #pragma unroll
            for (int m = 0; m < MP; ++m) {
                store_f2_agent(&ws_sxy[(b * N + pi0 + m) * 2],
                               xr[m] * scale, yr[m] * scale);
            }
        }
        asm volatile("s_waitcnt vmcnt(0)" ::: "memory");  // stores acked at LLC
        __syncthreads();                                   // all 4 waves done
        if (tid == 0) {
            __hip_atomic_fetch_add(c, 1u, __ATOMIC_RELAXED, __HIP_MEMORY_SCOPE_AGENT);
        }
        return;
    }

    // ---- tgt blocks: wait for this batch's 128 src writers ----
    if (tid == 0) {
        while (__hip_atomic_load(c, __ATOMIC_RELAXED, __HIP_MEMORY_SCOPE_AGENT)
               < (u32)SRCB) {
            __builtin_amdgcn_s_sleep(1);
        }
    }
    __syncthreads();   // orders the staging loads after the poll (SW+HW)

    // ---- phase-B staging: overwrite sj.xy with scaled src shape1 (LLC reads) ----
    for (int k = tid; k < N; k += TPB) {                 // 8 iters, 8B each
        const float2 v = load_f2_agent(&ws_sxy[(b * N + k) * 2]);
        *(float2*)&sj[k] = v;    // ds_write_b64 to .xy, momenta in .zw persist
    }
    float xsB[MP], ysB[MP];
    #pragma unroll
    for (int m = 0; m < MP; ++m) { xsB[m] = xr[m] * scale; ysB[m] = yr[m] * scale; }
    __syncthreads();

    // ---- phase B j-loop ----
    float bx[MP] = {0, 0, 0, 0}, by[MP] = {0, 0, 0, 0};
    #pragma unroll 4
    for (int t = 0; t < NJ; ++t) {
        const float4 s = sj[t * 64 + lane];
        #pragma unroll
        for (int m = 0; m < MP; ++m) {
            const float dx = xsB[m] - s.x, dy = ysB[m] - s.y;
            const float w  = exp2_neg(fmaf(dy, dy, dx * dx));
            bx[m] = fmaf(w, s.z, bx[m]);  by[m] = fmaf(w, s.w, by[m]);
        }
    }
    #pragma unroll
    for (int d = 1; d < 64; d <<= 1) {
        #pragma unroll
        for (int m = 0; m < MP; ++m) {
            bx[m] += __shfl_xor(bx[m], d);  by[m] += __shfl_xor(by[m], d);
        }
    }
    if (lane == 0) {
        const float4 o0 = make_float4(xr[0] + bx[0], yr[0] + by[0],
                                      xr[1] + bx[1], yr[1] + by[1]);
        const float4 o1 = make_float4(xr[2] + bx[2], yr[2] + by[2],
                                      xr[3] + bx[3], yr[3] + by[3]);
        ((float4*)out)[(b * N + pi0) >> 1]     = o0;
        ((float4*)out)[(b * N + pi0 + 2) >> 1] = o1;
    }
}

extern "C" void kernel_launch(void* const* d_in, const int* in_sizes, int n_in,
                              void* d_out, int out_size, void* d_ws, size_t ws_size,
                              hipStream_t stream)
{
    const float* momentum    = (const float*)d_in[0];
    const float* source_init = (const float*)d_in[1];
    const float* target_init = (const float*)d_in[2];
    const float* sigmaV2     = (const float*)d_in[3];
    float* out = (float*)d_out;

    const int B = in_sizes[0] / (N * 2);        // 4

    float* ws_sxy = (float*)d_ws;                                  // B*N*2 floats
    u32*   cnt    = (u32*)((char*)d_ws + (size_t)B * N * 2 * sizeof(float));

    // reset per-batch barrier counters (B * 64 bytes) every call
    // (required: harness poisons d_ws to 0xAA once before timing)
    (void)hipMemsetAsync(cnt, 0, (size_t)B * 16 * sizeof(u32), stream);

    deform_fused<<<dim3(B * BPB), dim3(TPB), 0, stream>>>(
        momentum, source_init, target_init, sigmaV2, ws_sxy, cnt, out);
}

// Round 11
// 20.150 us; speedup vs baseline: 3.1028x; 2.1018x over previous
//
#include <hip/hip_runtime.h>

// SingleCurveDeformLayer: 2-step Euler RBF flow, two kernels (proven best
// structure; fusion falsified 3x: R4 35.6us / R8 54.7us / R9 42.4us vs 21us).
//
//   step1: shape1_i = land_i + TAU*sum_j exp(-|land_i-src_j|^2/s2)*mom_j   (all 2N i)
//   step2: out_i    = shape1_i + TAU*sum_j exp(-|shape1_i-shape1_j|^2/s2)*mom_j  (tgt i)
//
// R10 lesson: inner-product factorization 2^(-ri)*2^(-rj)*2^(2L<i,j>)
// overflows for step2's deformed coords (|coord|~15-20 -> 2^(+650) * 2^(-650)
// = Inf*0 = NaN). The DIFFERENCE form (exponent always <= 0) is the safe one.
//
// This round: packed FP32 (VOP3P v_pk_*, 2 f32 ops/instr on CDNA4). Each lane
// processes a j-PAIR per iteration via ext_vector_type(2) arithmetic:
//   LDS:  sjx[k] = (x0*s, x1*s, y0*s, y1*s)   sjm[k] = (mx0,mx1,my0,my1)*TAU
//   loop: pk_sub dx, pk_sub dy, pk_mul, pk_fma d2, 2x v_exp(-), 2x pk_fma acc
//   ~28 cyc / 2 pairs (was ~40) -- exp (quarter-rate trans) now dominates.
// Geometry: TPB=256 (4 waves), full-wave j-split (NJP=16 pair-iters),
// step1 MP=4 (1024 blocks, 4/CU), step2 MP=2 (1024 blocks, 4/CU).

typedef float v2f __attribute__((ext_vector_type(2)));

constexpr int N    = 2048;            // n_src == n_tgt
constexpr int TPB  = 256;             // 4 waves
constexpr int NJP  = N / 2 / 64;      // 16 j-pair iterations per lane
constexpr float TAU   = 0.5f;         // 1/(N_T-1), N_T=3
constexpr float LOG2E = 1.44269504088896340736f;

__device__ inline float exp2_neg(float x) {   // 2^(-x), free neg modifier
    return __builtin_amdgcn_exp2f(-x);
}

template<int STEP, int MP>
__global__ __launch_bounds__(TPB, 4)
void deform_kernel(const float* __restrict__ momentum,
                   const float* __restrict__ source_init,
                   const float* __restrict__ target_init,
                   const float* __restrict__ sigmaV2,
                   float* __restrict__ shape1,   // ws: [B][2N][2] raw
                   float* __restrict__ out)      // [B][N][2]
{
    __shared__ float4 sjx[N / 2];   // (x0*s, x1*s, y0*s, y1*s) per j-pair: 16KB
    __shared__ float4 sjm[N / 2];   // (mx0, mx1, my0, my1)*TAU:          16KB

    constexpr int PPA = (TPB / 64) * MP;        // points per block

    const int tid  = threadIdx.x;
    const int ppb  = (STEP == 1) ? 2 * N : N;   // points per batch this step
    const int bpb  = ppb / PPA;                 // blocks per batch
    const int b    = blockIdx.x / bpb;
    const int pblk = blockIdx.x % bpb;

    const float scale = sqrtf(LOG2E / sigmaV2[0]);   // coord pre-scale

    // ---- stage j-pairs: transposed for packed math ----
    for (int k4 = tid; k4 < N / 2; k4 += TPB) {      // 4 iters, 2 pts each
        float4 p;
        if (STEP == 1) p = ((const float4*)source_init)[b * (N / 2) + k4];
        else           p = ((const float4*)(shape1 + (size_t)b * 2 * N * 2))[k4];
        const float4 m = ((const float4*)momentum)[b * (N / 2) + k4];
        sjx[k4] = make_float4(p.x * scale, p.z * scale, p.y * scale, p.w * scale);
        sjm[k4] = make_float4(m.x * TAU, m.z * TAU, m.y * TAU, m.w * TAU);
    }

    const int lane = tid & 63;            // j-pair chunk (full-wave split)
    const int g    = tid >> 6;            // wave id = point-group
    const int pi0  = pblk * PPA + g * MP; // wave's MP consecutive points

    // ---- wave's i-positions (wave-uniform 8B loads) ----
    float xi[MP], yi[MP];
    #pragma unroll
    for (int m = 0; m < MP; ++m) {
        float2 p;
        if (STEP == 1) {
            if (pi0 < N) p = ((const float2*)source_init)[b * N + pi0 + m];
            else         p = ((const float2*)target_init)[b * N + (pi0 - N) + m];
        } else {
            p = ((const float2*)shape1)[b * 2 * N + N + pi0 + m];
        }
        xi[m] = p.x;  yi[m] = p.y;
    }
    v2f xs2[MP], ys2[MP];
    #pragma unroll
    for (int m = 0; m < MP; ++m) {
        const float xs = xi[m] * scale, ys = yi[m] * scale;
        xs2[m].x = xs;  xs2[m].y = xs;
        ys2[m].x = ys;  ys2[m].y = ys;
    }
    __syncthreads();

    // ---- j-loop: packed f32, 2 pairs per iteration ----
    v2f ax2[MP], ay2[MP];
    #pragma unroll
    for (int m = 0; m < MP; ++m) {
        ax2[m].x = 0.f; ax2[m].y = 0.f;
        ay2[m].x = 0.f; ay2[m].y = 0.f;
    }
    #pragma unroll 4
    for (int t = 0; t < NJP; ++t) {
        const float4 sx = sjx[t * 64 + lane];
        const float4 sm = sjm[t * 64 + lane];
        v2f X, Y, MX, MY;
        X.x = sx.x;  X.y = sx.y;   Y.x = sx.z;  Y.y = sx.w;
        MX.x = sm.x; MX.y = sm.y;  MY.x = sm.z; MY.y = sm.w;
        #pragma unroll
        for (int m = 0; m < MP; ++m) {
            const v2f dx = xs2[m] - X;          // v_pk_add (neg)
            const v2f dy = ys2[m] - Y;
            v2f d2 = dx * dx;                    // v_pk_mul
            d2 += dy * dy;                       // v_pk_fma
            v2f w;
            w.x = exp2_neg(d2.x);                // v_exp_f32 (neg modifier)
            w.y = exp2_neg(d2.y);
            ax2[m] += w * MX;                    // v_pk_fma
            ay2[m] += w * MY;
        }
    }

    // ---- fold pair-halves, reduce across all 64 lanes ----
    float ax[MP], ay[MP];
    #pragma unroll
    for (int m = 0; m < MP; ++m) {
        ax[m] = ax2[m].x + ax2[m].y;
        ay[m] = ay2[m].x + ay2[m].y;
    }
    #pragma unroll
    for (int d = 1; d < 64; d <<= 1) {
        #pragma unroll
        for (int m = 0; m < MP; ++m) {
            ax[m] += __shfl_xor(ax[m], d);
            ay[m] += __shfl_xor(ay[m], d);
        }
    }

    if (lane == 0) {
        #pragma unroll
        for (int m = 0; m < MP; ++m) {
            const float2 o = make_float2(xi[m] + ax[m], yi[m] + ay[m]);
            if (STEP == 1) ((float2*)shape1)[b * 2 * N + pi0 + m] = o;
            else           ((float2*)out)[b * N + pi0 + m] = o;
        }
    }
}

extern "C" void kernel_launch(void* const* d_in, const int* in_sizes, int n_in,
                              void* d_out, int out_size, void* d_ws, size_t ws_size,
                              hipStream_t stream)
{
    const float* momentum    = (const float*)d_in[0];
    const float* source_init = (const float*)d_in[1];
    const float* target_init = (const float*)d_in[2];
    const float* sigmaV2     = (const float*)d_in[3];
    float* out    = (float*)d_out;
    float* shape1 = (float*)d_ws;   // B * 4096 * 2 floats = 128 KB

    const int B = in_sizes[0] / (N * 2);   // 4

    dim3 blk(TPB);
    // step 1: MP=4, PPA=16 -> B * 4096/16 = 1024 blocks (4/CU)
    deform_kernel<1, 4><<<dim3(B * (2 * N / 16)), blk, 0, stream>>>(
        momentum, source_init, target_init, sigmaV2, shape1, out);
    // step 2: MP=2, PPA=8  -> B * 2048/8  = 1024 blocks (4/CU)
    deform_kernel<2, 2><<<dim3(B * (N / 8)), blk, 0, stream>>>(
        momentum, source_init, target_init, sigmaV2, shape1, out);
}